// Round 4
// baseline (10919.892 us; speedup 1.0000x reference)
//
#include <hip/hip_runtime.h>
#include <math.h>

#define N_HID   1024
#define NBATCH  128
#define TSTEPS  500
#define DT      0.05f
#define THETA   0.1f

// WG = 256 threads computes a 16-batch x 32-col output tile, k-split 8.
// Thread tile: 4 batches x 4 cols. Grid = 8 btiles x 32 ctiles = 256 WGs,
// 1 per CU (cooperative launch guarantees co-residency).
// Summation order: ascending k within each 128-seg, then segments 0..7
// ascending — identical to the v2 kernel that validated absmax 0.0.
#define B_WG   16
#define C_WG   32
#define KSPL   8
#define KSEG   (N_HID / KSPL)      // 128
#define NWG    ((NBATCH / B_WG) * (N_HID / C_WG))   // 256

// hy stored transposed: hyT[n_hid][n_batch], ping-ponged between two buffers.
// Cross-WG dependency per step is only within a btile group (32 WGs) ->
// 8 independent 32-WG barriers, device-scope atomics (XCD-safe).

__global__ __launch_bounds__(256, 1) void persist_kernel(
    const float* __restrict__ x,
    const float* __restrict__ W,       // (1024,1024) row-major [k][c]
    const float* __restrict__ x2h,
    const float* __restrict__ bias,
    const float* __restrict__ gam,
    const float* __restrict__ eps,
    float* __restrict__ hyT0,          // (1024,128), zero-initialized
    float* __restrict__ hyT1,
    float* __restrict__ uout,          // (128,1024) output
    unsigned int* __restrict__ tot,
    unsigned int* __restrict__ bar,    // 8 counters, stride 64 u32
    float alpha, float oma)
{
    __shared__ float sh_hyT[N_HID * B_WG];            // 64 KB: [k][16b]
    __shared__ float sh_part[KSPL * B_WG * C_WG];     // 16 KB: [ks][b][c]
    __shared__ float sh_out[C_WG * (B_WG + 1)];       // padded transpose buf
    __shared__ unsigned int sh_cnt;

    const int tid = threadIdx.x;
    if (tid == 0) sh_cnt = 0u;

    // XCD swizzle: XCD (bid&7) owns 4 consecutive col-tiles -> its 128-col,
    // 512 KB W slice stays hot in that XCD's L2 across all steps.
    const int bid   = blockIdx.x;
    const int xcd   = bid & 7;
    const int idx   = bid >> 3;            // 0..31
    const int ctile = xcd * 4 + (idx & 3); // 0..31
    const int btile = idx >> 2;            // 0..7  (barrier group)
    const int c0g   = ctile * C_WG;
    const int b0    = btile * B_WG;

    // GEMM thread mapping (fixed across steps)
    const int cg  = tid & 7;
    const int bg  = (tid >> 3) & 3;
    const int ks  = tid >> 5;
    const int bl0 = bg * 4;
    const int k0  = ks * KSEG;
    const float* Wp = W + (size_t)k0 * N_HID + c0g + cg * 4;

    // Epilogue thread mapping (fixed across steps): two elements per thread.
    const int bl_a = tid >> 5;           // 0..7
    const int bl_b = 8 + (tid >> 5);     // 8..15
    const int c_e  = tid & 31;
    const int cgl  = c0g + c_e;
    // hoist per-column constants out of the time loop
    const float x2h_c  = x2h[cgl];
    const float bias_c = bias[cgl];
    const float gam_c  = gam[cgl];
    const float eps_c  = eps[cgl];
    const float* xrow_a = x + (size_t)(b0 + bl_a) * TSTEPS;
    const float* xrow_b = x + (size_t)(b0 + bl_b) * TSTEPS;

    // persistent per-thread state
    float hz_a = 0.f, hz_b = 0.f, u_a = 0.f, u_b = 0.f;
    unsigned int spikes = 0;

    unsigned int* mybar = bar + (btile << 6);   // 256B-spaced counters

    const float* bufs[2] = { hyT0, hyT1 };

    for (int t = 0; t < TSTEPS; ++t) {
        const float* src = bufs[t & 1];
        float*       dst = (float*)bufs[(t + 1) & 1];

        // ---- stage hyT[:, b0:b0+16] -> LDS (64 KB), coalesced float4 ----
        {
            const float4* g4 = (const float4*)src;   // row = 32 float4
            float4* s4 = (float4*)sh_hyT;
            #pragma unroll
            for (int it = 0; it < 16; ++it) {
                const int i = it * 256 + tid;        // 0..4095
                const int k = i >> 2, ch = i & 3;
                s4[i] = g4[k * 32 + btile * 4 + ch];
            }
        }
        __syncthreads();

        // ---- register-blocked GEMM: 4b x 4c per thread, kseg = 128 ----
        float acc[4][4];
        #pragma unroll
        for (int i = 0; i < 4; ++i)
            #pragma unroll
            for (int j = 0; j < 4; ++j) acc[i][j] = 0.f;

        #pragma unroll 8
        for (int kk = 0; kk < KSEG; ++kk) {
            const float4 hv = *(const float4*)(&sh_hyT[(k0 + kk) * B_WG + bl0]);
            const float4 wv = *(const float4*)(Wp + (size_t)kk * N_HID);
            acc[0][0] = fmaf(hv.x, wv.x, acc[0][0]);
            acc[0][1] = fmaf(hv.x, wv.y, acc[0][1]);
            acc[0][2] = fmaf(hv.x, wv.z, acc[0][2]);
            acc[0][3] = fmaf(hv.x, wv.w, acc[0][3]);
            acc[1][0] = fmaf(hv.y, wv.x, acc[1][0]);
            acc[1][1] = fmaf(hv.y, wv.y, acc[1][1]);
            acc[1][2] = fmaf(hv.y, wv.z, acc[1][2]);
            acc[1][3] = fmaf(hv.y, wv.w, acc[1][3]);
            acc[2][0] = fmaf(hv.z, wv.x, acc[2][0]);
            acc[2][1] = fmaf(hv.z, wv.y, acc[2][1]);
            acc[2][2] = fmaf(hv.z, wv.z, acc[2][2]);
            acc[2][3] = fmaf(hv.z, wv.w, acc[2][3]);
            acc[3][0] = fmaf(hv.w, wv.x, acc[3][0]);
            acc[3][1] = fmaf(hv.w, wv.y, acc[3][1]);
            acc[3][2] = fmaf(hv.w, wv.z, acc[3][2]);
            acc[3][3] = fmaf(hv.w, wv.w, acc[3][3]);
        }

        #pragma unroll
        for (int bi = 0; bi < 4; ++bi) {
            float4 v = make_float4(acc[bi][0], acc[bi][1], acc[bi][2], acc[bi][3]);
            *(float4*)(&sh_part[((ks * B_WG) + bl0 + bi) * C_WG + cg * 4]) = v;
        }
        __syncthreads();

        // ---- reduce k-segments (ascending) + fused cell update ----
        // half A: element (bl_a, c_e)
        {
            float sum = sh_part[(0 * B_WG + bl_a) * C_WG + c_e];
            #pragma unroll
            for (int s2 = 1; s2 < KSPL; ++s2)
                sum += sh_part[(s2 * B_WG + bl_a) * C_WG + c_e];
            const float xb  = xrow_a[t];
            const float pre = tanhf(fmaf(xb, x2h_c, sum) + bias_c);
            const float hyv = sh_hyT[cgl * B_WG + bl_a];
            hz_a = fmaf(DT, pre - gam_c * hyv - eps_c * hz_a, hz_a);
            const float hyn = fmaf(DT, hz_a, hyv);
            const int s = ((hyn - THETA) > 0.f) ? 1 : 0;
            u_a = fmaf(u_a, alpha, (float)s * oma);
            spikes += (unsigned)s;
            sh_out[c_e * (B_WG + 1) + bl_a] = hyn;
        }
        // half B: element (bl_b, c_e)
        {
            float sum = sh_part[(0 * B_WG + bl_b) * C_WG + c_e];
            #pragma unroll
            for (int s2 = 1; s2 < KSPL; ++s2)
                sum += sh_part[(s2 * B_WG + bl_b) * C_WG + c_e];
            const float xb  = xrow_b[t];
            const float pre = tanhf(fmaf(xb, x2h_c, sum) + bias_c);
            const float hyv = sh_hyT[cgl * B_WG + bl_b];
            hz_b = fmaf(DT, pre - gam_c * hyv - eps_c * hz_b, hz_b);
            const float hyn = fmaf(DT, hz_b, hyv);
            const int s = ((hyn - THETA) > 0.f) ? 1 : 0;
            u_b = fmaf(u_b, alpha, (float)s * oma);
            spikes += (unsigned)s;
            sh_out[c_e * (B_WG + 1) + bl_b] = hyn;
        }
        __syncthreads();

        // ---- coalesced transposed write: dst[c0g+c2][b0:b0+16] ----
        {
            const int c2 = tid >> 3;
            const int b2 = (tid & 7) * 2;
            float* d = dst + (size_t)(c0g + c2) * NBATCH + b0 + b2;
            d[0] = sh_out[c2 * (B_WG + 1) + b2];
            d[1] = sh_out[c2 * (B_WG + 1) + b2 + 1];
        }
        __syncthreads();   // all global writes issued (waitcnt before barrier)

        // ---- btile-group barrier (32 WGs), device scope ----
        if (tid == 0) {
            __hip_atomic_fetch_add(mybar, 1u, __ATOMIC_RELEASE,
                                   __HIP_MEMORY_SCOPE_AGENT);
            const unsigned int target = 32u * (unsigned int)(t + 1);
            while (__hip_atomic_load(mybar, __ATOMIC_ACQUIRE,
                                     __HIP_MEMORY_SCOPE_AGENT) < target) {
                __builtin_amdgcn_s_sleep(1);
            }
        }
        __syncthreads();
    }

    // ---- final: write u, reduce spike count ----
    uout[(size_t)(b0 + bl_a) * N_HID + cgl] = u_a;
    uout[(size_t)(b0 + bl_b) * N_HID + cgl] = u_b;

    unsigned int s = spikes;
    s += __shfl_down(s, 32);
    s += __shfl_down(s, 16);
    s += __shfl_down(s, 8);
    s += __shfl_down(s, 4);
    s += __shfl_down(s, 2);
    s += __shfl_down(s, 1);
    if ((tid & 63) == 0) atomicAdd(&sh_cnt, s);
    __syncthreads();
    if (tid == 0) atomicAdd(tot, sh_cnt);
}

__global__ void init_kernel(float* hyT0, unsigned int* tot, unsigned int* bar)
{
    const int i = blockIdx.x * blockDim.x + threadIdx.x;
    const int n = NBATCH * N_HID;
    if (i < n) hyT0[i] = 0.f;
    if (i == 0) *tot = 0u;
    if (i < 8 * 64) bar[i] = 0u;
}

__global__ void final_kernel(const unsigned int* __restrict__ tot,
                             float* __restrict__ out_rate)
{
    if (threadIdx.x == 0 && blockIdx.x == 0) {
        const double denom = (double)NBATCH * (double)TSTEPS * (double)N_HID;
        *out_rate = (float)((double)(*tot) / denom);
    }
}

extern "C" void kernel_launch(void* const* d_in, const int* in_sizes, int n_in,
                              void* d_out, int out_size, void* d_ws, size_t ws_size,
                              hipStream_t stream)
{
    const float* x    = (const float*)d_in[0];
    const float* h2h  = (const float*)d_in[1];
    const float* x2h  = (const float*)d_in[2];
    const float* bias = (const float*)d_in[3];
    const float* gam  = (const float*)d_in[4];
    const float* eps  = (const float*)d_in[5];

    float* out = (float*)d_out;            // u: [0,131072), rate at [131072]

    float* hyT0 = (float*)d_ws;
    float* hyT1 = hyT0 + (size_t)NBATCH * N_HID;
    unsigned int* tot = (unsigned int*)(hyT1 + (size_t)NBATCH * N_HID);
    unsigned int* bar = tot + 64;          // 8 counters, 64-u32 stride

    init_kernel<<<dim3((NBATCH * N_HID + 255) / 256), dim3(256), 0, stream>>>(
        hyT0, tot, bar);

    float alpha = expf(-1.0f / 20.0f);
    float oma   = 1.0f - alpha;

    void* args[] = {
        (void*)&x, (void*)&h2h, (void*)&x2h, (void*)&bias, (void*)&gam,
        (void*)&eps, (void*)&hyT0, (void*)&hyT1, (void*)&out, (void*)&tot,
        (void*)&bar, (void*)&alpha, (void*)&oma
    };
    hipLaunchCooperativeKernel((const void*)persist_kernel,
                               dim3(NWG), dim3(256), args, 0, stream);

    final_kernel<<<dim3(1), dim3(64), 0, stream>>>(tot, out + (size_t)NBATCH * N_HID);
}

// Round 5
// 3762.415 us; speedup vs baseline: 2.9024x; 2.9024x over previous
//
#include <hip/hip_runtime.h>
#include <math.h>

#define N_HID   1024
#define NBATCH  128
#define TSTEPS  500
#define DT      0.05f
#define THETA   0.1f

// WG = 256 threads computes an 8-batch x 64-col tile, k-split 8.
// Thread tile: 4 batches x 4 cols (bg in {0,1}, cg in 0..15), KSEG=128.
// Grid = 16 btiles x 16 ctiles = 256 WGs, 1/CU (cooperative).
// Per-output FP summation order: fmaf ascending k within each 128-seg,
// segments 0..7 summed ascending — identical to the bit-exact v2/v3.
#define B_WG   8
#define C_WG   64
#define KSPL   8
#define KSEG   (N_HID / KSPL)      // 128
#define NGRP   (NBATCH / B_WG)     // 16 barrier groups
#define NCT    (N_HID / C_WG)      // 16 col tiles
#define NWG    (NGRP * NCT)        // 256

typedef unsigned long long u64;

// hy ping-pongs between two transposed buffers hyT[n_hid][n_batch].
// Cross-WG hy exchange goes through the Infinity Cache via relaxed
// agent-scope (sc1) u64 loads/stores — no L2 writeback/invalidate, so W
// stays L2-resident across all 500 steps. Barrier counters: relaxed
// agent-scope atomics (16 arrivals per group).

__global__ __launch_bounds__(256, 1) void persist_kernel(
    const float* __restrict__ x,
    const float* __restrict__ W,       // (1024,1024) row-major [k][c]
    const float* __restrict__ x2h,
    const float* __restrict__ bias,
    const float* __restrict__ gam,
    const float* __restrict__ eps,
    float* __restrict__ hyT0,          // (1024,128), zero-initialized
    float* __restrict__ hyT1,
    float* __restrict__ uout,          // (128,1024) output
    unsigned int* __restrict__ tot,
    unsigned int* __restrict__ bar,    // 16 counters, stride 64 u32
    float alpha, float oma)
{
    __shared__ float sh_hyT[N_HID * B_WG];            // 32 KB: [k][8b]
    __shared__ float sh_part[KSPL * B_WG * C_WG];     // 16 KB: [ks][b][c]
    __shared__ float sh_out[C_WG * (B_WG + 1)];       // 2.25 KB transpose buf
    __shared__ unsigned int sh_cnt;

    const int tid = threadIdx.x;
    if (tid == 0) sh_cnt = 0u;

    // XCD swizzle: XCD (bid&7) owns 2 consecutive col-tiles (128 cols,
    // 512 KB W slice) -> L2-resident across all steps (no invalidates now).
    const int bid   = blockIdx.x;
    const int xcd   = bid & 7;
    const int idx   = bid >> 3;            // 0..31
    const int ctile = xcd * 2 + (idx & 1); // 0..15
    const int btile = idx >> 1;            // 0..15  (barrier group)
    const int c0g   = ctile * C_WG;
    const int b0    = btile * B_WG;

    // GEMM thread mapping (fixed across steps)
    const int cg  = tid & 15;          // 16 col-groups of 4
    const int bg  = (tid >> 4) & 1;    // 2 batch-groups of 4
    const int ks  = tid >> 5;          // 8 k-segments
    const int bl0 = bg * 4;
    const int k0  = ks * KSEG;
    const float* Wp = W + (size_t)k0 * N_HID + c0g + cg * 4;

    // Epilogue mapping (fixed): two outputs per thread.
    const int bl_a = tid >> 6;           // 0..3
    const int bl_b = 4 + bl_a;           // 4..7
    const int c_e  = tid & 63;
    const int cgl  = c0g + c_e;
    const float x2h_c  = x2h[cgl];
    const float bias_c = bias[cgl];
    const float gam_c  = gam[cgl];
    const float eps_c  = eps[cgl];
    const float* xrow_a = x + (size_t)(b0 + bl_a) * TSTEPS;
    const float* xrow_b = x + (size_t)(b0 + bl_b) * TSTEPS;

    // persistent per-thread state (hz, u live in registers all 500 steps)
    float hz_a = 0.f, hz_b = 0.f, u_a = 0.f, u_b = 0.f;
    unsigned int spikes = 0;

    unsigned int* mybar = bar + (btile << 6);   // 256B-spaced counters

    const float* bufs[2] = { hyT0, hyT1 };

    for (int t = 0; t < TSTEPS; ++t) {
        const float* src = bufs[t & 1];
        float*       dst = (float*)bufs[(t + 1) & 1];

        // ---- stage hyT[:, b0:b0+8] -> LDS via IF$-coherent u64 loads ----
        // 4096 u64 total; 16 per thread, batched so they pipeline.
        {
            u64 tmp[16];
            #pragma unroll
            for (int it = 0; it < 16; ++it) {
                const int i    = it * 256 + tid;   // 0..4095
                const int k    = i >> 2;
                const int pair = i & 3;
                const u64* sp = (const u64*)(src + (size_t)k * NBATCH + b0) + pair;
                tmp[it] = __hip_atomic_load(sp, __ATOMIC_RELAXED,
                                            __HIP_MEMORY_SCOPE_AGENT);
            }
            u64* s64 = (u64*)sh_hyT;
            #pragma unroll
            for (int it = 0; it < 16; ++it)
                s64[it * 256 + tid] = tmp[it];
        }
        __syncthreads();

        // ---- register-blocked GEMM: 4b x 4c per thread, kseg = 128 ----
        float acc[4][4];
        #pragma unroll
        for (int i = 0; i < 4; ++i)
            #pragma unroll
            for (int j = 0; j < 4; ++j) acc[i][j] = 0.f;

        #pragma unroll 8
        for (int kk = 0; kk < KSEG; ++kk) {
            const float4 hv = *(const float4*)(&sh_hyT[(k0 + kk) * B_WG + bl0]);
            const float4 wv = *(const float4*)(Wp + (size_t)kk * N_HID);
            acc[0][0] = fmaf(hv.x, wv.x, acc[0][0]);
            acc[0][1] = fmaf(hv.x, wv.y, acc[0][1]);
            acc[0][2] = fmaf(hv.x, wv.z, acc[0][2]);
            acc[0][3] = fmaf(hv.x, wv.w, acc[0][3]);
            acc[1][0] = fmaf(hv.y, wv.x, acc[1][0]);
            acc[1][1] = fmaf(hv.y, wv.y, acc[1][1]);
            acc[1][2] = fmaf(hv.y, wv.z, acc[1][2]);
            acc[1][3] = fmaf(hv.y, wv.w, acc[1][3]);
            acc[2][0] = fmaf(hv.z, wv.x, acc[2][0]);
            acc[2][1] = fmaf(hv.z, wv.y, acc[2][1]);
            acc[2][2] = fmaf(hv.z, wv.z, acc[2][2]);
            acc[2][3] = fmaf(hv.z, wv.w, acc[2][3]);
            acc[3][0] = fmaf(hv.w, wv.x, acc[3][0]);
            acc[3][1] = fmaf(hv.w, wv.y, acc[3][1]);
            acc[3][2] = fmaf(hv.w, wv.z, acc[3][2]);
            acc[3][3] = fmaf(hv.w, wv.w, acc[3][3]);
        }

        #pragma unroll
        for (int bi = 0; bi < 4; ++bi) {
            float4 v = make_float4(acc[bi][0], acc[bi][1], acc[bi][2], acc[bi][3]);
            *(float4*)(&sh_part[((ks * B_WG) + bl0 + bi) * C_WG + cg * 4]) = v;
        }
        __syncthreads();

        // ---- reduce k-segments (ascending) + fused cell update ----
        {
            float sum = sh_part[(0 * B_WG + bl_a) * C_WG + c_e];
            #pragma unroll
            for (int s2 = 1; s2 < KSPL; ++s2)
                sum += sh_part[(s2 * B_WG + bl_a) * C_WG + c_e];
            const float xb  = xrow_a[t];
            const float pre = tanhf(fmaf(xb, x2h_c, sum) + bias_c);
            const float hyv = sh_hyT[cgl * B_WG + bl_a];
            hz_a = fmaf(DT, pre - gam_c * hyv - eps_c * hz_a, hz_a);
            const float hyn = fmaf(DT, hz_a, hyv);
            const int s = ((hyn - THETA) > 0.f) ? 1 : 0;
            u_a = fmaf(u_a, alpha, (float)s * oma);
            spikes += (unsigned)s;
            sh_out[c_e * (B_WG + 1) + bl_a] = hyn;
        }
        {
            float sum = sh_part[(0 * B_WG + bl_b) * C_WG + c_e];
            #pragma unroll
            for (int s2 = 1; s2 < KSPL; ++s2)
                sum += sh_part[(s2 * B_WG + bl_b) * C_WG + c_e];
            const float xb  = xrow_b[t];
            const float pre = tanhf(fmaf(xb, x2h_c, sum) + bias_c);
            const float hyv = sh_hyT[cgl * B_WG + bl_b];
            hz_b = fmaf(DT, pre - gam_c * hyv - eps_c * hz_b, hz_b);
            const float hyn = fmaf(DT, hz_b, hyv);
            const int s = ((hyn - THETA) > 0.f) ? 1 : 0;
            u_b = fmaf(u_b, alpha, (float)s * oma);
            spikes += (unsigned)s;
            sh_out[c_e * (B_WG + 1) + bl_b] = hyn;
        }
        __syncthreads();   // all 512 sh_out entries valid

        // ---- transposed write via IF$-coherent u64 stores ----
        // dst[c0g+c2][b0 + b2 .. b2+1], one u64 per thread (256 total).
        {
            const int c2 = tid >> 2;           // 0..63
            const int b2 = (tid & 3) * 2;      // 0,2,4,6
            u64 v;
            float2 f2 = make_float2(sh_out[c2 * (B_WG + 1) + b2],
                                    sh_out[c2 * (B_WG + 1) + b2 + 1]);
            __builtin_memcpy(&v, &f2, 8);
            u64* dp = (u64*)(dst + (size_t)(c0g + c2) * NBATCH + b0 + b2);
            __hip_atomic_store(dp, v, __ATOMIC_RELAXED,
                               __HIP_MEMORY_SCOPE_AGENT);
        }
        __syncthreads();   // drains vmcnt: all stores acked at IF$

        // ---- btile-group barrier (16 WGs), relaxed agent atomics ----
        if (tid == 0) {
            __hip_atomic_fetch_add(mybar, 1u, __ATOMIC_RELAXED,
                                   __HIP_MEMORY_SCOPE_AGENT);
            const unsigned int target = 16u * (unsigned int)(t + 1);
            while (__hip_atomic_load(mybar, __ATOMIC_RELAXED,
                                     __HIP_MEMORY_SCOPE_AGENT) < target) {
                __builtin_amdgcn_s_sleep(1);
            }
        }
        __syncthreads();
    }

    // ---- final: write u, reduce spike count ----
    uout[(size_t)(b0 + bl_a) * N_HID + cgl] = u_a;
    uout[(size_t)(b0 + bl_b) * N_HID + cgl] = u_b;

    unsigned int s = spikes;
    s += __shfl_down(s, 32);
    s += __shfl_down(s, 16);
    s += __shfl_down(s, 8);
    s += __shfl_down(s, 4);
    s += __shfl_down(s, 2);
    s += __shfl_down(s, 1);
    if ((tid & 63) == 0) atomicAdd(&sh_cnt, s);
    __syncthreads();
    if (tid == 0) atomicAdd(tot, sh_cnt);
}

__global__ void init_kernel(float* hyT0, unsigned int* tot, unsigned int* bar)
{
    const int i = blockIdx.x * blockDim.x + threadIdx.x;
    const int n = NBATCH * N_HID;
    if (i < n) hyT0[i] = 0.f;
    if (i == 0) *tot = 0u;
    if (i < NGRP * 64) bar[i] = 0u;
}

__global__ void final_kernel(const unsigned int* __restrict__ tot,
                             float* __restrict__ out_rate)
{
    if (threadIdx.x == 0 && blockIdx.x == 0) {
        const double denom = (double)NBATCH * (double)TSTEPS * (double)N_HID;
        *out_rate = (float)((double)(*tot) / denom);
    }
}

extern "C" void kernel_launch(void* const* d_in, const int* in_sizes, int n_in,
                              void* d_out, int out_size, void* d_ws, size_t ws_size,
                              hipStream_t stream)
{
    const float* x    = (const float*)d_in[0];
    const float* h2h  = (const float*)d_in[1];
    const float* x2h  = (const float*)d_in[2];
    const float* bias = (const float*)d_in[3];
    const float* gam  = (const float*)d_in[4];
    const float* eps  = (const float*)d_in[5];

    float* out = (float*)d_out;            // u: [0,131072), rate at [131072]

    float* hyT0 = (float*)d_ws;
    float* hyT1 = hyT0 + (size_t)NBATCH * N_HID;
    unsigned int* tot = (unsigned int*)(hyT1 + (size_t)NBATCH * N_HID);
    unsigned int* bar = tot + 64;          // 16 counters, 64-u32 stride

    init_kernel<<<dim3((NBATCH * N_HID + 255) / 256), dim3(256), 0, stream>>>(
        hyT0, tot, bar);

    float alpha = expf(-1.0f / 20.0f);
    float oma   = 1.0f - alpha;

    void* args[] = {
        (void*)&x, (void*)&h2h, (void*)&x2h, (void*)&bias, (void*)&gam,
        (void*)&eps, (void*)&hyT0, (void*)&hyT1, (void*)&out, (void*)&tot,
        (void*)&bar, (void*)&alpha, (void*)&oma
    };
    hipLaunchCooperativeKernel((const void*)persist_kernel,
                               dim3(NWG), dim3(256), args, 0, stream);

    final_kernel<<<dim3(1), dim3(64), 0, stream>>>(tot, out + (size_t)NBATCH * N_HID);
}

// Round 8
// 3665.131 us; speedup vs baseline: 2.9794x; 1.0265x over previous
//
#include <hip/hip_runtime.h>
#include <math.h>

typedef unsigned long long u64;
typedef unsigned int u32;

#define N_HID   1024
#define NBATCH  128
#define TSTEPS  500
#define DT      0.05f
#define THETA   0.1f

// Geometry identical to bit-exact R5: WG = 256 thr, 8-batch x 64-col tile,
// thread tile 4b x 4c, k-split 8 (KSEG=128). 16 btile groups x 16 ctiles
// = 256 WGs, 1/CU cooperative. FP summation order per output unchanged.
#define B_WG   8
#define C_WG   64
#define KSPL   8
#define KSEG   (N_HID / KSPL)      // 128
#define NGRP   (NBATCH / B_WG)     // 16 groups
#define NCT    (N_HID / C_WG)      // 16 producers (ctiles) per group
#define NWG    (NGRP * NCT)        // 256

// Sync: NO barrier. Per-group, per-producer epoch flags (dataflow).
// Producer (btile, ctile) publishes flag = t+1 after its hy(t+1) stores are
// drained. Consumer wave w polls only its 4 producers (ctiles 4w..4w+3).
// All flag/data traffic uses the R5-proven AGENT-scope relaxed atomics (IF$).
#define CTRL_TOT    0
#define CTRL_GRP    64                      // group g: flags at +g*64+p
#define CTRL_WORDS  (CTRL_GRP + NGRP * 64)

__device__ __forceinline__ u32 a_ld32(const u32* p) {
    return __hip_atomic_load(p, __ATOMIC_RELAXED, __HIP_MEMORY_SCOPE_AGENT);
}
__device__ __forceinline__ void a_st32(u32* p, u32 v) {
    __hip_atomic_store(p, v, __ATOMIC_RELAXED, __HIP_MEMORY_SCOPE_AGENT);
}
__device__ __forceinline__ u64 a_ld64(const u64* p) {
    return __hip_atomic_load(p, __ATOMIC_RELAXED, __HIP_MEMORY_SCOPE_AGENT);
}
__device__ __forceinline__ void a_st64(u64* p, u64 v) {
    __hip_atomic_store(p, v, __ATOMIC_RELAXED, __HIP_MEMORY_SCOPE_AGENT);
}

__global__ __launch_bounds__(256, 1) void persist_kernel(
    const float* __restrict__ x,
    const float* __restrict__ W,       // (1024,1024) row-major [k][c]
    const float* __restrict__ x2h,
    const float* __restrict__ bias,
    const float* __restrict__ gam,
    const float* __restrict__ eps,
    float* __restrict__ hyT0,          // (1024,128) ping
    float* __restrict__ hyT1,          // (1024,128) pong
    float* __restrict__ uout,          // (128,1024) output
    u32* __restrict__ ctrl,
    float alpha, float oma)
{
    __shared__ float sh_hyT[N_HID * B_WG];            // 32 KB [k][8b]
    __shared__ float sh_part[KSPL * B_WG * C_WG];     // 16 KB [ks][b][c]
    __shared__ float sh_out[C_WG * (B_WG + 1)];       // transpose buf
    __shared__ u32 sh_cnt;

    const int tid = threadIdx.x;
    if (tid == 0) sh_cnt = 0u;

    // XCD swizzle (R5): XCD (bid&7) owns 2 ctiles -> 512 KB W slice hot in L2.
    const int bid   = blockIdx.x;
    const int xcd   = bid & 7;
    const int idx   = bid >> 3;
    const int ctile = xcd * 2 + (idx & 1);
    const int btile = idx >> 1;
    const int c0g   = ctile * C_WG;
    const int b0    = btile * B_WG;

    // GEMM thread mapping (R5)
    const int cg  = tid & 15;
    const int bg  = (tid >> 4) & 1;
    const int ks  = tid >> 5;          // 0..7
    const int bl0 = bg * 4;
    const int k0  = ks * KSEG;
    const float* Wp = W + (size_t)k0 * N_HID + c0g + cg * 4;

    // wave-level dataflow mapping: wave wv stages/consumes hy rows
    // [256*wv, 256*wv+256) -> producers (64-row chunks) 4*wv .. 4*wv+3
    const int wv   = tid >> 6;         // 0..3
    const int lane = tid & 63;
    u32* flags = ctrl + CTRL_GRP + (btile << 6);   // 16 flags, one 64B line
    u32* myflag_pollp = flags + (4 * wv + (lane & 3));

    // epilogue mapping (R5): two outputs per thread
    const int bl_a = tid >> 6;
    const int bl_b = 4 + bl_a;
    const int c_e  = tid & 63;
    const int cgl  = c0g + c_e;
    const float x2h_c  = x2h[cgl];
    const float bias_c = bias[cgl];
    const float gam_c  = gam[cgl];
    const float eps_c  = eps[cgl];
    const float* xrow_a = x + (size_t)(b0 + bl_a) * TSTEPS;
    const float* xrow_b = x + (size_t)(b0 + bl_b) * TSTEPS;

    float hz_a = 0.f, hz_b = 0.f, u_a = 0.f, u_b = 0.f;
    u32 spikes = 0;

    const float* src = hyT0;
    float*       dst = hyT1;

    for (int t = 0; t < TSTEPS; ++t) {
        // ---- acquire hy(t) rows for this wave ----
        if (t == 0) {
            // hy(0) == 0 exactly: zero-fill (no memory read, no sync needed)
            u64* s64 = (u64*)sh_hyT;
            #pragma unroll
            for (int it = 0; it < 16; ++it) s64[it * 256 + tid] = 0ull;
            __syncthreads();   // whole tile zeroed before any wave's fma
        } else {
            // dataflow: wait only for this wave's 4 producers (epoch >= t)
            while (!__all(a_ld32(myflag_pollp) >= (u32)t))
                __builtin_amdgcn_s_sleep(1);
            // stage rows [256*wv, 256*wv+256) x 8 batches (8 KB), IF$ loads
            u64 tmp[16];
            #pragma unroll
            for (int it = 0; it < 16; ++it) {
                const int i    = it * 64 + lane;        // 0..1023
                const int k    = (wv << 8) + (i >> 2);
                const int pair = i & 3;
                const u64* sp = (const u64*)(src + (size_t)k * NBATCH + b0) + pair;
                tmp[it] = a_ld64(sp);
            }
            u64* s64 = (u64*)sh_hyT;
            #pragma unroll
            for (int it = 0; it < 16; ++it)
                s64[(wv << 10) + it * 64 + lane] = tmp[it];
            // no barrier: this wave's fma reads only rows it just wrote
            // (ds_write -> ds_read same-wave ordering via lgkmcnt)
        }

        // ---- register-blocked GEMM: 4b x 4c, kseg = 128 (order-exact) ----
        float acc[4][4];
        #pragma unroll
        for (int i = 0; i < 4; ++i)
            #pragma unroll
            for (int jj = 0; jj < 4; ++jj) acc[i][jj] = 0.f;

        #pragma unroll 8
        for (int kk = 0; kk < KSEG; ++kk) {
            const float4 hv = *(const float4*)(&sh_hyT[(k0 + kk) * B_WG + bl0]);
            const float4 wv4 = *(const float4*)(Wp + (size_t)kk * N_HID);
            acc[0][0] = fmaf(hv.x, wv4.x, acc[0][0]);
            acc[0][1] = fmaf(hv.x, wv4.y, acc[0][1]);
            acc[0][2] = fmaf(hv.x, wv4.z, acc[0][2]);
            acc[0][3] = fmaf(hv.x, wv4.w, acc[0][3]);
            acc[1][0] = fmaf(hv.y, wv4.x, acc[1][0]);
            acc[1][1] = fmaf(hv.y, wv4.y, acc[1][1]);
            acc[1][2] = fmaf(hv.y, wv4.z, acc[1][2]);
            acc[1][3] = fmaf(hv.y, wv4.w, acc[1][3]);
            acc[2][0] = fmaf(hv.z, wv4.x, acc[2][0]);
            acc[2][1] = fmaf(hv.z, wv4.y, acc[2][1]);
            acc[2][2] = fmaf(hv.z, wv4.z, acc[2][2]);
            acc[2][3] = fmaf(hv.z, wv4.w, acc[2][3]);
            acc[3][0] = fmaf(hv.w, wv4.x, acc[3][0]);
            acc[3][1] = fmaf(hv.w, wv4.y, acc[3][1]);
            acc[3][2] = fmaf(hv.w, wv4.z, acc[3][2]);
            acc[3][3] = fmaf(hv.w, wv4.w, acc[3][3]);
        }

        #pragma unroll
        for (int bi = 0; bi < 4; ++bi) {
            float4 v = make_float4(acc[bi][0], acc[bi][1], acc[bi][2], acc[bi][3]);
            *(float4*)(&sh_part[((ks * B_WG) + bl0 + bi) * C_WG + cg * 4]) = v;
        }
        __syncthreads();   // SYNC1: all segments + all staged rows visible

        // ---- reduce k-segments (ascending, R5 order) + fused cell ----
        {
            float sum = sh_part[(0 * B_WG + bl_a) * C_WG + c_e];
            #pragma unroll
            for (int s2 = 1; s2 < KSPL; ++s2)
                sum += sh_part[(s2 * B_WG + bl_a) * C_WG + c_e];
            const float xb  = xrow_a[t];
            const float pre = tanhf(fmaf(xb, x2h_c, sum) + bias_c);
            const float hyv = sh_hyT[cgl * B_WG + bl_a];
            hz_a = fmaf(DT, pre - gam_c * hyv - eps_c * hz_a, hz_a);
            const float hyn = fmaf(DT, hz_a, hyv);
            const int s = ((hyn - THETA) > 0.f) ? 1 : 0;
            u_a = fmaf(u_a, alpha, (float)s * oma);
            spikes += (u32)s;
            sh_out[c_e * (B_WG + 1) + bl_a] = hyn;
        }
        {
            float sum = sh_part[(0 * B_WG + bl_b) * C_WG + c_e];
            #pragma unroll
            for (int s2 = 1; s2 < KSPL; ++s2)
                sum += sh_part[(s2 * B_WG + bl_b) * C_WG + c_e];
            const float xb  = xrow_b[t];
            const float pre = tanhf(fmaf(xb, x2h_c, sum) + bias_c);
            const float hyv = sh_hyT[cgl * B_WG + bl_b];
            hz_b = fmaf(DT, pre - gam_c * hyv - eps_c * hz_b, hz_b);
            const float hyn = fmaf(DT, hz_b, hyv);
            const int s = ((hyn - THETA) > 0.f) ? 1 : 0;
            u_b = fmaf(u_b, alpha, (float)s * oma);
            spikes += (u32)s;
            sh_out[c_e * (B_WG + 1) + bl_b] = hyn;
        }
        __syncthreads();   // sh_out complete

        // ---- transposed hy(t+1) write via IF$ u64 stores (R5-proven) ----
        {
            const int c2 = tid >> 3;           // 0..31  (2 rows per thread)
            #pragma unroll
            for (int rr = 0; rr < 2; ++rr) {
                const int c3 = c2 + rr * 32;   // 0..63
                const int b2 = (tid & 7);      // 8 u64 lanes? -> 1 u64 each
                // 64 rows x 4 u64 = 256 u64 total; thread handles one u64
                // index: row c3, pair (tid&7)>>1 ... simpler: flat mapping
                (void)c3; (void)b2;
            }
        }
        // flat mapping: 256 u64 stores, one per thread
        {
            const int c2 = tid >> 2;           // 0..63 row
            const int b2 = (tid & 3) * 2;      // 0,2,4,6
            float2 f2 = make_float2(sh_out[c2 * (B_WG + 1) + b2],
                                    sh_out[c2 * (B_WG + 1) + b2 + 1]);
            u64 v;
            __builtin_memcpy(&v, &f2, 8);
            a_st64((u64*)(dst + (size_t)(c0g + c2) * NBATCH + b0 + b2), v);
        }
        __syncthreads();   // SYNC2: every wave's stores drained (vmcnt(0))

        // ---- publish epoch t+1 (single writer per flag) ----
        if (tid == 0) a_st32(flags + ctile, (u32)(t + 1));

        float* tmpp = (float*)src; src = dst; dst = tmpp;
    }

    // ---- final: u out, spike-count reduce ----
    uout[(size_t)(b0 + bl_a) * N_HID + cgl] = u_a;
    uout[(size_t)(b0 + bl_b) * N_HID + cgl] = u_b;

    u32 s = spikes;
    s += __shfl_down(s, 32);
    s += __shfl_down(s, 16);
    s += __shfl_down(s, 8);
    s += __shfl_down(s, 4);
    s += __shfl_down(s, 2);
    s += __shfl_down(s, 1);
    if ((tid & 63) == 0) atomicAdd(&sh_cnt, s);
    __syncthreads();
    if (tid == 0) atomicAdd(ctrl + CTRL_TOT, sh_cnt);
}

__global__ void init_kernel(u32* ctrl)
{
    const int i = blockIdx.x * blockDim.x + threadIdx.x;
    if (i < CTRL_WORDS) {
        __hip_atomic_store(ctrl + i, 0u, __ATOMIC_RELAXED,
                           __HIP_MEMORY_SCOPE_AGENT);
    }
}

__global__ void final_kernel(const u32* __restrict__ ctrl,
                             float* __restrict__ out_rate)
{
    if (threadIdx.x == 0 && blockIdx.x == 0) {
        const double denom = (double)NBATCH * (double)TSTEPS * (double)N_HID;
        *out_rate = (float)((double)ctrl[CTRL_TOT] / denom);
    }
}

extern "C" void kernel_launch(void* const* d_in, const int* in_sizes, int n_in,
                              void* d_out, int out_size, void* d_ws, size_t ws_size,
                              hipStream_t stream)
{
    const float* x    = (const float*)d_in[0];
    const float* h2h  = (const float*)d_in[1];
    const float* x2h  = (const float*)d_in[2];
    const float* bias = (const float*)d_in[3];
    const float* gam  = (const float*)d_in[4];
    const float* eps  = (const float*)d_in[5];

    float* out = (float*)d_out;            // u: [0,131072), rate at [131072]

    float* hyT0 = (float*)d_ws;
    float* hyT1 = hyT0 + (size_t)NBATCH * N_HID;
    u32*   ctrl = (u32*)(hyT1 + (size_t)NBATCH * N_HID);

    init_kernel<<<dim3((CTRL_WORDS + 255) / 256), dim3(256), 0, stream>>>(ctrl);

    float alpha = expf(-1.0f / 20.0f);
    float oma   = 1.0f - alpha;

    void* args[] = {
        (void*)&x, (void*)&h2h, (void*)&x2h, (void*)&bias, (void*)&gam,
        (void*)&eps, (void*)&hyT0, (void*)&hyT1, (void*)&out, (void*)&ctrl,
        (void*)&alpha, (void*)&oma
    };
    hipLaunchCooperativeKernel((const void*)persist_kernel,
                               dim3(NWG), dim3(256), args, 0, stream);

    final_kernel<<<dim3(1), dim3(64), 0, stream>>>(
        ctrl, out + (size_t)NBATCH * N_HID);
}